// Round 12
// baseline (34.491 us; speedup 1.0000x reference)
//
#include <hip/hip_runtime.h>
#include <math.h>

// Problem constants: D=2048, K=4096, C=1000, W=4096
constexpr int KN = 4096;
constexpr int DN = 2048;
constexpr int CN = 1000;
constexpr int WN = 4096;

// Butterfly reductions — result valid in ALL lanes.
__device__ __forceinline__ float waveSum(float v) {
#pragma unroll
    for (int o = 32; o > 0; o >>= 1) v += __shfl_xor(v, o, 64);
    return v;
}
__device__ __forceinline__ float waveMax(float v) {
#pragma unroll
    for (int o = 32; o > 0; o >>= 1) v = fmaxf(v, __shfl_xor(v, o, 64));
    return v;
}

// Stage 1: per-wave rows, no block barriers (R7-identical; 32 waves/CU).
constexpr int S1_DIST_BLOCKS = KN / 4;   // 1024
constexpr int S1_CE_BLOCKS   = KN / 4;   // 1024

__global__ __launch_bounds__(256) void stage1_kernel(
    const float* __restrict__ deep, const float* __restrict__ nmat,
    const float* __restrict__ cls, const int* __restrict__ target,
    float* __restrict__ d_arr, float* __restrict__ ce_arr)
{
    const int b    = blockIdx.x;
    const int tid  = threadIdx.x;
    const int wv   = tid >> 6;
    const int lane = tid & 63;

    if (b < S1_DIST_BLOCKS) {
        // ---- distance row: 512 float4, 8 per lane ----
        const int row = b * 4 + wv;
        const float4* nrow = (const float4*)(nmat + (size_t)row * DN);
        const float4* df   = (const float4*)deep;
        float acc = 0.f;
#pragma unroll
        for (int c = 0; c < 8; ++c) {
            const int i = lane + 64 * c;
            const float4 a = df[i];
            const float4 x = nrow[i];
            const float e0 = a.x - x.x, e1 = a.y - x.y, e2 = a.z - x.z, e3 = a.w - x.w;
            acc += e0 * e0 + e1 * e1 + e2 * e2 + e3 * e3;
        }
        acc = waveSum(acc);
        if (lane == 0) d_arr[row] = sqrtf(acc);
    } else {
        // ---- CE row: 250 float4, <=4 per lane, padded with -inf ----
        const int row = (b - S1_DIST_BLOCKS) * 4 + wv;
        const float4* x4 = (const float4*)(cls + (size_t)row * CN);
        float4 v[4];
#pragma unroll
        for (int j = 0; j < 4; ++j) {
            const int i = lane + 64 * j;
            v[j] = (i < CN / 4) ? x4[i]
                                : make_float4(-INFINITY, -INFINITY, -INFINITY, -INFINITY);
        }
        float mx = -INFINITY;
#pragma unroll
        for (int j = 0; j < 4; ++j)
            mx = fmaxf(mx, fmaxf(fmaxf(v[j].x, v[j].y), fmaxf(v[j].z, v[j].w)));
        const float m = waveMax(mx);
        float s = 0.f;
#pragma unroll
        for (int j = 0; j < 4; ++j)    // exp(-inf - m) == 0, pads vanish
            s += __expf(v[j].x - m) + __expf(v[j].y - m)
               + __expf(v[j].z - m) + __expf(v[j].w - m);
        s = waveSum(s);
        if (lane == 0)
            ce_arr[row] = m + __logf(s) - cls[(size_t)row * CN + target[0]];
    }
}

// Stage 2 (R12): R7-identical inner loop (1024 blocks x 256 thr, 1 row/wave,
// double-buffered register batches). Final reduce MERGED in via validated
// last-block pattern: UC-store partial -> vmcnt(0) drain -> relaxed
// fetch_add -> last block reduces all 1024 partials with UC loads.
// Block 0 resets the counter at entry (first arrival is >=8us later: every
// block streams 64KB of w first; all blocks co-resident at 4/CU).
constexpr int S2_BLOCK_THREADS = 256;
constexpr int S2_ROWS_PER_BLK  = 4;                       // 4 waves x 1 row
constexpr int S2_BLOCKS        = WN / S2_ROWS_PER_BLK;    // 1024

__global__ __launch_bounds__(S2_BLOCK_THREADS, 4) void stage2_kernel(
    const float* __restrict__ wmat, const float* __restrict__ d_arr,
    const float* __restrict__ ce_arr, float* __restrict__ part,
    unsigned int* __restrict__ cnt, float* __restrict__ out)
{
    __shared__ float wpart[4];
    __shared__ float red2[4];
    __shared__ int   sLast;
    const int tid  = threadIdx.x;
    const int wv   = tid >> 6;
    const int lane = tid & 63;

    if (blockIdx.x == 0 && tid == 0)
        __hip_atomic_store(cnt, 0u, __ATOMIC_RELAXED, __HIP_MEMORY_SCOPE_AGENT);

    const int row = blockIdx.x * S2_ROWS_PER_BLK + wv;
    const float4* wrow = (const float4*)(wmat + (size_t)row * KN);
    const float4* d4   = (const float4*)d_arr;
    const float4* c4   = (const float4*)ce_arr;

    float4 wa[4], wb[4];
#pragma unroll
    for (int j = 0; j < 4; ++j) wa[j] = wrow[lane + 64 * j];

    // two accumulator sets to shorten dependency chains
    float es0 = 0.f, ec0 = 0.f, fs0 = 0.f;
    float es1 = 0.f, ec1 = 0.f, fs1 = 0.f;

#pragma unroll
    for (int c = 0; c < 16; c += 4) {
        if (c + 4 < 16) {
#pragma unroll
            for (int j = 0; j < 4; ++j) wb[j] = wrow[lane + 64 * (c + 4 + j)];
        }
#pragma unroll
        for (int j = 0; j < 4; ++j) {
            const int i = lane + 64 * (c + j);
            const float4 dv = d4[i];
            const float4 cv = c4[i];
            const float4 a  = wa[j];
            float t, e;
            t = a.x * dv.x; fs0 += t; e = __expf(-t); es0 += e; ec0 += e * cv.x;
            t = a.y * dv.y; fs1 += t; e = __expf(-t); es1 += e; ec1 += e * cv.y;
            t = a.z * dv.z; fs0 += t; e = __expf(-t); es0 += e; ec0 += e * cv.z;
            t = a.w * dv.w; fs1 += t; e = __expf(-t); es1 += e; ec1 += e * cv.w;
        }
#pragma unroll
        for (int j = 0; j < 4; ++j) wa[j] = wb[j];
    }

    float es = waveSum(es0 + es1);
    float ec = waveSum(ec0 + ec1);
    float fs = waveSum(fs0 + fs1);

    if (lane == 0) wpart[wv] = ec / es + fs;   // no-max softmax: s in (-70,0]
    __syncthreads();

    // ---- publish block partial, last-block final reduce ----
    if (tid == 0) {
        const float psum = wpart[0] + wpart[1] + wpart[2] + wpart[3];
        __hip_atomic_store(&part[blockIdx.x], psum,
                           __ATOMIC_RELAXED, __HIP_MEMORY_SCOPE_AGENT);
        asm volatile("s_waitcnt vmcnt(0)" ::: "memory");
        const unsigned prev = __hip_atomic_fetch_add(cnt, 1u, __ATOMIC_RELAXED,
                                                     __HIP_MEMORY_SCOPE_AGENT);
        sLast = (prev == (unsigned)(S2_BLOCKS - 1)) ? 1 : 0;
    }
    __syncthreads();
    if (sLast) {
        // 1024 partials / 256 threads = 4 UC loads each (fresh lines, LLC)
        float acc = 0.f;
#pragma unroll
        for (int j = 0; j < 4; ++j)
            acc += __hip_atomic_load(&part[tid + S2_BLOCK_THREADS * j],
                                     __ATOMIC_RELAXED, __HIP_MEMORY_SCOPE_AGENT);
        acc = waveSum(acc);
        if (lane == 0) red2[wv] = acc;
        __syncthreads();
        if (tid == 0) out[0] = red2[0] + red2[1] + red2[2] + red2[3];
    }
}

extern "C" void kernel_launch(void* const* d_in, const int* in_sizes, int n_in,
                              void* d_out, int out_size, void* d_ws, size_t ws_size,
                              hipStream_t stream) {
    const float* deep   = (const float*)d_in[0];   // [1, D]
    const float* cls    = (const float*)d_in[1];   // [K, C]
    const int*   target = (const int*)d_in[2];     // [1]
    const float* nmat   = (const float*)d_in[3];   // [K, D]
    const float* wmat   = (const float*)d_in[4];   // [W, K]

    float* ws     = (float*)d_ws;
    float* d_arr  = ws;            // [K]
    float* ce_arr = ws + KN;       // [K]
    float* part   = ws + 2 * KN;   // [1024]
    unsigned int* cnt = (unsigned int*)(ws + 2 * KN + S2_BLOCKS);  // [1]

    stage1_kernel<<<S1_DIST_BLOCKS + S1_CE_BLOCKS, 256, 0, stream>>>(
        deep, nmat, cls, target, d_arr, ce_arr);
    stage2_kernel<<<S2_BLOCKS, S2_BLOCK_THREADS, 0, stream>>>(
        wmat, d_arr, ce_arr, part, cnt, (float*)d_out);
}

// Round 14
// 27.316 us; speedup vs baseline: 1.2627x; 1.2627x over previous
//
#include <hip/hip_runtime.h>
#include <math.h>

// Problem constants: D=2048, K=4096, C=1000, W=4096
constexpr int KN = 4096;
constexpr int DN = 2048;
constexpr int CN = 1000;
constexpr int WN = 4096;

// Butterfly reductions — result valid in ALL lanes.
__device__ __forceinline__ float waveSum(float v) {
#pragma unroll
    for (int o = 32; o > 0; o >>= 1) v += __shfl_xor(v, o, 64);
    return v;
}
__device__ __forceinline__ float waveMax(float v) {
#pragma unroll
    for (int o = 32; o > 0; o >>= 1) v = fmaxf(v, __shfl_xor(v, o, 64));
    return v;
}

// Stage 1: per-wave rows, no block barriers.
//   blocks [0, KN/4):          4 distance rows/block (one per wave)
//   blocks [KN/4, 2*KN/4):     4 CE rows/block
constexpr int S1_DIST_BLOCKS = KN / 4;   // 1024
constexpr int S1_CE_BLOCKS   = KN / 4;   // 1024

__global__ __launch_bounds__(256) void stage1_kernel(
    const float* __restrict__ deep, const float* __restrict__ nmat,
    const float* __restrict__ cls, const int* __restrict__ target,
    float* __restrict__ d_arr, float* __restrict__ ce_arr)
{
    const int b    = blockIdx.x;
    const int tid  = threadIdx.x;
    const int wv   = tid >> 6;
    const int lane = tid & 63;

    if (b < S1_DIST_BLOCKS) {
        // ---- distance row: 512 float4, 8 per lane ----
        const int row = b * 4 + wv;
        const float4* nrow = (const float4*)(nmat + (size_t)row * DN);
        const float4* df   = (const float4*)deep;
        float acc = 0.f;
#pragma unroll
        for (int c = 0; c < 8; ++c) {
            const int i = lane + 64 * c;
            const float4 a = df[i];
            const float4 x = nrow[i];
            const float e0 = a.x - x.x, e1 = a.y - x.y, e2 = a.z - x.z, e3 = a.w - x.w;
            acc += e0 * e0 + e1 * e1 + e2 * e2 + e3 * e3;
        }
        acc = waveSum(acc);
        if (lane == 0) d_arr[row] = sqrtf(acc);
    } else {
        // ---- CE row: 250 float4, <=4 per lane, padded with -inf ----
        const int row = (b - S1_DIST_BLOCKS) * 4 + wv;
        const float4* x4 = (const float4*)(cls + (size_t)row * CN);
        float4 v[4];
#pragma unroll
        for (int j = 0; j < 4; ++j) {
            const int i = lane + 64 * j;
            v[j] = (i < CN / 4) ? x4[i]
                                : make_float4(-INFINITY, -INFINITY, -INFINITY, -INFINITY);
        }
        float mx = -INFINITY;
#pragma unroll
        for (int j = 0; j < 4; ++j)
            mx = fmaxf(mx, fmaxf(fmaxf(v[j].x, v[j].y), fmaxf(v[j].z, v[j].w)));
        const float m = waveMax(mx);
        float s = 0.f;
#pragma unroll
        for (int j = 0; j < 4; ++j)    // exp(-inf - m) == 0, pads vanish
            s += __expf(v[j].x - m) + __expf(v[j].y - m)
               + __expf(v[j].z - m) + __expf(v[j].w - m);
        s = waveSum(s);
        if (lane == 0)
            ce_arr[row] = m + __logf(s) - cls[(size_t)row * CN + target[0]];
    }
}

// Stage 2: 1024 blocks x 256 threads, 1 w-row per wave -> 4096 waves,
// up to 8 blocks/CU (no LDS). Explicit double-buffered register batches
// (4 x float4) keep >=4 wave-level loads in flight. d/ce read direct from
// global (32 KB total, L1-hot). No-max softmax exact-safe: s=-w*d in (-70,0].
constexpr int S2_BLOCK_THREADS = 256;
constexpr int S2_ROWS_PER_BLK  = 4;                       // 4 waves x 1 row
constexpr int S2_BLOCKS        = WN / S2_ROWS_PER_BLK;    // 1024

__global__ __launch_bounds__(S2_BLOCK_THREADS, 4) void stage2_kernel(
    const float* __restrict__ wmat, const float* __restrict__ d_arr,
    const float* __restrict__ ce_arr, float* __restrict__ part)
{
    __shared__ float wpart[4];
    const int tid  = threadIdx.x;
    const int wv   = tid >> 6;
    const int lane = tid & 63;

    const int row = blockIdx.x * S2_ROWS_PER_BLK + wv;
    const float4* wrow = (const float4*)(wmat + (size_t)row * KN);
    const float4* d4   = (const float4*)d_arr;
    const float4* c4   = (const float4*)ce_arr;

    float4 wa[4], wb[4];
#pragma unroll
    for (int j = 0; j < 4; ++j) wa[j] = wrow[lane + 64 * j];

    // two accumulator sets to shorten dependency chains
    float es0 = 0.f, ec0 = 0.f, fs0 = 0.f;
    float es1 = 0.f, ec1 = 0.f, fs1 = 0.f;

#pragma unroll
    for (int c = 0; c < 16; c += 4) {
        // issue next batch of w loads first (stays in flight under compute)
        if (c + 4 < 16) {
#pragma unroll
            for (int j = 0; j < 4; ++j) wb[j] = wrow[lane + 64 * (c + 4 + j)];
        }
#pragma unroll
        for (int j = 0; j < 4; ++j) {
            const int i = lane + 64 * (c + j);
            const float4 dv = d4[i];
            const float4 cv = c4[i];
            const float4 a  = wa[j];
            float t, e;
            t = a.x * dv.x; fs0 += t; e = __expf(-t); es0 += e; ec0 += e * cv.x;
            t = a.y * dv.y; fs1 += t; e = __expf(-t); es1 += e; ec1 += e * cv.y;
            t = a.z * dv.z; fs0 += t; e = __expf(-t); es0 += e; ec0 += e * cv.z;
            t = a.w * dv.w; fs1 += t; e = __expf(-t); es1 += e; ec1 += e * cv.w;
        }
#pragma unroll
        for (int j = 0; j < 4; ++j) wa[j] = wb[j];
    }

    float es = waveSum(es0 + es1);
    float ec = waveSum(ec0 + ec1);
    float fs = waveSum(fs0 + fs1);

    if (lane == 0) wpart[wv] = ec / es + fs;
    __syncthreads();
    if (tid == 0)
        part[blockIdx.x] = wpart[0] + wpart[1] + wpart[2] + wpart[3];
}

// Stage 3: one block, deterministic reduce of the 1024 block partials.
__global__ __launch_bounds__(512) void stage3_kernel(
    const float* __restrict__ part, float* __restrict__ out)
{
    __shared__ float red[8];
    const int tid  = threadIdx.x;
    const int wv   = tid >> 6;
    const int lane = tid & 63;
    float v = part[tid] + part[tid + 512];
    v = waveSum(v);
    if (lane == 0) red[wv] = v;
    __syncthreads();
    if (tid == 0) {
        float acc = 0.f;
#pragma unroll
        for (int j = 0; j < 8; ++j) acc += red[j];
        out[0] = acc;
    }
}

extern "C" void kernel_launch(void* const* d_in, const int* in_sizes, int n_in,
                              void* d_out, int out_size, void* d_ws, size_t ws_size,
                              hipStream_t stream) {
    const float* deep   = (const float*)d_in[0];   // [1, D]
    const float* cls    = (const float*)d_in[1];   // [K, C]
    const int*   target = (const int*)d_in[2];     // [1]
    const float* nmat   = (const float*)d_in[3];   // [K, D]
    const float* wmat   = (const float*)d_in[4];   // [W, K]

    float* ws     = (float*)d_ws;
    float* d_arr  = ws;            // [K]
    float* ce_arr = ws + KN;       // [K]
    float* part   = ws + 2 * KN;   // [1024]

    stage1_kernel<<<S1_DIST_BLOCKS + S1_CE_BLOCKS, 256, 0, stream>>>(
        deep, nmat, cls, target, d_arr, ce_arr);
    stage2_kernel<<<S2_BLOCKS, S2_BLOCK_THREADS, 0, stream>>>(
        wmat, d_arr, ce_arr, part);
    stage3_kernel<<<1, 512, 0, stream>>>(part, (float*)d_out);
}